// Round 1
// baseline (740.883 us; speedup 1.0000x reference)
//
#include <hip/hip_runtime.h>
#include <math.h>

#define EPSF 1e-12f

// Problem constants: N=64, C=512, P=40*40=1600, K=64
// ws layout (bytes):
//   a'        : N*K*P fp32 = 26,214,400  @ 0
//   Wt        : C*K fp32   = 131,072     @ 26,214,400
//   asum_part : N*7*K fp32 = 114,688     @ 26,345,472
//   asum      : N*K fp32   = 16,384      @ 26,460,160
//   rownorm2  : N*K fp32   = 16,384      @ 26,476,544
//   gn        : N fp32     = 256         @ 26,492,928

// ---------------------------------------------------------------- K0: Wt[c][k] = W[k][c]
__global__ __launch_bounds__(256) void k0_wt(const float* __restrict__ W,
                                             float* __restrict__ Wt) {
    int idx = blockIdx.x * 256 + threadIdx.x;
    if (idx < 64 * 512) {
        int k = idx >> 9;
        int c = idx & 511;
        Wt[c * 64 + k] = W[idx];
    }
}

// ---------------------------------------------------------------- K2: logits + softmax + a' + asum partials
// block = 256 threads, one pixel per thread. grid = (7 ptiles, 64 n).
// logits[k,p] = rn[p] * sum_c W[k,c]*x[c,p]; ss accumulated in the same c-loop.
__global__ __launch_bounds__(256) void k2_logits(const float* __restrict__ x,
                                                 const float* __restrict__ Wt,
                                                 float* __restrict__ a_out,
                                                 float* __restrict__ asum_part) {
    const int n  = blockIdx.y;
    const int px = blockIdx.x;
    const int p  = px * 256 + threadIdx.x;
    const bool active = (p < 1600);

    __shared__ float red[64];
    if (threadIdx.x < 64) red[threadIdx.x] = 0.f;

    float4 acc[16];
    float rn = 0.f;
    if (active) {
        #pragma unroll
        for (int i = 0; i < 16; i++) acc[i] = make_float4(0.f, 0.f, 0.f, 0.f);
        float ss = 0.f;
        const float* xp = x + n * 512 * 1600 + p;
        #pragma unroll 8
        for (int c = 0; c < 512; c++) {
            float xv = xp[c * 1600];
            ss = fmaf(xv, xv, ss);
            const float4* wr = (const float4*)(Wt + c * 64);  // wave-uniform address
            #pragma unroll
            for (int i = 0; i < 16; i++) {
                float4 w = wr[i];
                acc[i].x = fmaf(w.x, xv, acc[i].x);
                acc[i].y = fmaf(w.y, xv, acc[i].y);
                acc[i].z = fmaf(w.z, xv, acc[i].z);
                acc[i].w = fmaf(w.w, xv, acc[i].w);
            }
        }
        rn = 1.f / fmaxf(sqrtf(ss), EPSF);

        // softmax over the 64 k values (all in registers)
        float m = -3.4e38f;
        #pragma unroll
        for (int i = 0; i < 16; i++) {
            acc[i].x *= rn; acc[i].y *= rn; acc[i].z *= rn; acc[i].w *= rn;
            m = fmaxf(m, fmaxf(fmaxf(acc[i].x, acc[i].y), fmaxf(acc[i].z, acc[i].w)));
        }
        float s = 0.f;
        #pragma unroll
        for (int i = 0; i < 16; i++) {
            acc[i].x = __expf(acc[i].x - m); s += acc[i].x;
            acc[i].y = __expf(acc[i].y - m); s += acc[i].y;
            acc[i].z = __expf(acc[i].z - m); s += acc[i].z;
            acc[i].w = __expf(acc[i].w - m); s += acc[i].w;
        }
        float is = 1.f / s;
        #pragma unroll
        for (int i = 0; i < 16; i++) {
            acc[i].x *= is; acc[i].y *= is; acc[i].z *= is; acc[i].w *= is;
        }
        // store a' = a * rn  (rn folded so GEMM2 runs on raw x)
        float* ap = a_out + (n * 64) * 1600 + p;
        #pragma unroll
        for (int i = 0; i < 16; i++) {
            ap[(i * 4 + 0) * 1600] = acc[i].x * rn;
            ap[(i * 4 + 1) * 1600] = acc[i].y * rn;
            ap[(i * 4 + 2) * 1600] = acc[i].z * rn;
            ap[(i * 4 + 3) * 1600] = acc[i].w * rn;
        }
    }
    __syncthreads();
    if (active) {
        #pragma unroll
        for (int i = 0; i < 16; i++) {
            atomicAdd(&red[i * 4 + 0], acc[i].x);
            atomicAdd(&red[i * 4 + 1], acc[i].y);
            atomicAdd(&red[i * 4 + 2], acc[i].z);
            atomicAdd(&red[i * 4 + 3], acc[i].w);
        }
    }
    __syncthreads();
    if (threadIdx.x < 64)
        asum_part[(n * 7 + px) * 64 + threadIdx.x] = red[threadIdx.x];
}

// ---------------------------------------------------------------- K2.5: asum[n,k] = sum of 7 partials
__global__ __launch_bounds__(256) void k25_asum(const float* __restrict__ asum_part,
                                                float* __restrict__ asum) {
    int idx = blockIdx.x * 256 + threadIdx.x;
    if (idx < 4096) {
        int n = idx >> 6, k = idx & 63;
        float s = 0.f;
        #pragma unroll
        for (int pt = 0; pt < 7; pt++) s += asum_part[(n * 7 + pt) * 64 + k];
        asum[idx] = s;
    }
}

// ---------------------------------------------------------------- K3: vlad_raw[n,k,c] += sum_p a'[k,p]*x[c,p]
// block: 64k x 128c tile of one n, over 800 p. grid = (4 ctiles, 64 n, 2 pchunks).
// thread tile 4k x 8c. LDS-transposed staging of a' and x (p-major).
__global__ __launch_bounds__(256) void k3_vlad(const float* __restrict__ x,
                                               const float* __restrict__ a_ws,
                                               float* __restrict__ vout) {
    const int n  = blockIdx.y;
    const int c0 = blockIdx.x * 128;
    const int p0 = blockIdx.z * 800;
    const int tid = threadIdx.x;

    __shared__ float lds_a[16 * 68];   // [p][k], stride 68
    __shared__ float lds_x[16 * 132];  // [p][c], stride 132

    const int tk = tid >> 4;   // 0..15 -> k0 = tk*4
    const int tc = tid & 15;   // 0..15 -> c  = tc*8

    float acc[4][8];
    #pragma unroll
    for (int i = 0; i < 4; i++)
        #pragma unroll
        for (int j = 0; j < 8; j++) acc[i][j] = 0.f;

    const int ka = tid >> 2, p4 = tid & 3;  // a'-staging role
    const int cs = tid >> 1, ph = tid & 1;  // x-staging role
    const float* agp = a_ws + (n * 64 + ka) * 1600 + p0 + p4 * 4;
    const float* xgp = x + (n * 512 + c0 + cs) * 1600 + p0 + ph * 8;

    for (int pc = 0; pc < 800; pc += 16) {
        __syncthreads();
        {   // stage a': 16p x 64k
            float4 v = *(const float4*)(agp + pc);
            lds_a[(p4 * 4 + 0) * 68 + ka] = v.x;
            lds_a[(p4 * 4 + 1) * 68 + ka] = v.y;
            lds_a[(p4 * 4 + 2) * 68 + ka] = v.z;
            lds_a[(p4 * 4 + 3) * 68 + ka] = v.w;
        }
        {   // stage x: 16p x 128c
            float4 v0 = *(const float4*)(xgp + pc);
            float4 v1 = *(const float4*)(xgp + pc + 4);
            lds_x[(ph * 8 + 0) * 132 + cs] = v0.x;
            lds_x[(ph * 8 + 1) * 132 + cs] = v0.y;
            lds_x[(ph * 8 + 2) * 132 + cs] = v0.z;
            lds_x[(ph * 8 + 3) * 132 + cs] = v0.w;
            lds_x[(ph * 8 + 4) * 132 + cs] = v1.x;
            lds_x[(ph * 8 + 5) * 132 + cs] = v1.y;
            lds_x[(ph * 8 + 6) * 132 + cs] = v1.z;
            lds_x[(ph * 8 + 7) * 132 + cs] = v1.w;
        }
        __syncthreads();
        #pragma unroll
        for (int p = 0; p < 16; p++) {
            float4 av = *(const float4*)(lds_a + p * 68 + tk * 4);
            float4 x0 = *(const float4*)(lds_x + p * 132 + tc * 8);
            float4 x1 = *(const float4*)(lds_x + p * 132 + tc * 8 + 4);
            float aa[4] = {av.x, av.y, av.z, av.w};
            float xx[8] = {x0.x, x0.y, x0.z, x0.w, x1.x, x1.y, x1.z, x1.w};
            #pragma unroll
            for (int i = 0; i < 4; i++)
                #pragma unroll
                for (int j = 0; j < 8; j++)
                    acc[i][j] = fmaf(aa[i], xx[j], acc[i][j]);
        }
    }
    // 2 pchunks -> exactly two commutative fp32 adds per address: deterministic
    float* vb = vout + n * 32768 + (tk * 4) * 512 + c0 + tc * 8;
    #pragma unroll
    for (int i = 0; i < 4; i++)
        #pragma unroll
        for (int j = 0; j < 8; j++)
            atomicAdd(vb + i * 512 + j, acc[i][j]);
}

// ---------------------------------------------------------------- K4a: rownorm2[n,k] = sum_c (raw - asum*cent)^2
__global__ __launch_bounds__(256) void k4a_rownorm(const float* __restrict__ vraw,
                                                   const float* __restrict__ asum,
                                                   const float* __restrict__ cent,
                                                   float* __restrict__ rn2) {
    int row  = blockIdx.x * 4 + (threadIdx.x >> 6);  // row = n*64+k, one wave per row
    int lane = threadIdx.x & 63;
    int k = row & 63;
    const float4* vp = (const float4*)(vraw + row * 512 + lane * 8);
    const float4* cp = (const float4*)(cent + k * 512 + lane * 8);
    float as = asum[row];
    float4 v0 = vp[0], v1 = vp[1], c0 = cp[0], c1 = cp[1];
    float s = 0.f, t;
    t = v0.x - as * c0.x; s = fmaf(t, t, s);
    t = v0.y - as * c0.y; s = fmaf(t, t, s);
    t = v0.z - as * c0.z; s = fmaf(t, t, s);
    t = v0.w - as * c0.w; s = fmaf(t, t, s);
    t = v1.x - as * c1.x; s = fmaf(t, t, s);
    t = v1.y - as * c1.y; s = fmaf(t, t, s);
    t = v1.z - as * c1.z; s = fmaf(t, t, s);
    t = v1.w - as * c1.w; s = fmaf(t, t, s);
    #pragma unroll
    for (int off = 32; off > 0; off >>= 1) s += __shfl_down(s, off, 64);
    if (lane == 0) rn2[row] = s;
}

// ---------------------------------------------------------------- K4b: gn[n] from rownorms only
// After intra-norm each row contributes rownorm2/max(rownorm,eps)^2 to the global norm^2.
__global__ __launch_bounds__(64) void k4b_gn(const float* __restrict__ rn2,
                                             float* __restrict__ gn) {
    int n = blockIdx.x, k = threadIdx.x;
    float t = rn2[n * 64 + k];
    float d = fmaxf(sqrtf(t), EPSF);
    float r = t / (d * d);
    #pragma unroll
    for (int off = 32; off > 0; off >>= 1) r += __shfl_down(r, off, 64);
    if (k == 0) gn[n] = fmaxf(sqrtf(r), EPSF);
}

// ---------------------------------------------------------------- K4c: out = (raw - asum*cent) / (max(rownorm,eps)*gn)
__global__ __launch_bounds__(256) void k4c_final(float* __restrict__ vout,
                                                 const float* __restrict__ asum,
                                                 const float* __restrict__ cent,
                                                 const float* __restrict__ rn2,
                                                 const float* __restrict__ gn) {
    int gid = blockIdx.x * 256 + threadIdx.x;  // 524288 threads, float4 each
    int idx4 = gid * 4;
    int row = idx4 >> 9;
    int n = row >> 6, k = row & 63, c = idx4 & 511;
    float4 v  = *(const float4*)(vout + idx4);
    float4 cv = *(const float4*)(cent + k * 512 + c);
    float as = asum[row];
    float inv = 1.f / (fmaxf(sqrtf(rn2[row]), EPSF) * gn[n]);
    v.x = (v.x - as * cv.x) * inv;
    v.y = (v.y - as * cv.y) * inv;
    v.z = (v.z - as * cv.z) * inv;
    v.w = (v.w - as * cv.w) * inv;
    *(float4*)(vout + idx4) = v;
}

// ----------------------------------------------------------------
extern "C" void kernel_launch(void* const* d_in, const int* in_sizes, int n_in,
                              void* d_out, int out_size, void* d_ws, size_t ws_size,
                              hipStream_t stream) {
    const float* x    = (const float*)d_in[0];  // [64,512,40,40]
    const float* W    = (const float*)d_in[1];  // [64,512,1,1]
    const float* cent = (const float*)d_in[2];  // [64,512]
    float* out = (float*)d_out;                 // [64, 32768]
    char* ws = (char*)d_ws;

    float* a_ws  = (float*)(ws + 0);
    float* Wt    = (float*)(ws + 26214400);
    float* asump = (float*)(ws + 26345472);
    float* asum  = (float*)(ws + 26460160);
    float* rn2   = (float*)(ws + 26476544);
    float* gn    = (float*)(ws + 26492928);

    hipLaunchKernelGGL(k0_wt,      dim3(128),      dim3(256), 0, stream, W, Wt);
    hipLaunchKernelGGL(k2_logits,  dim3(7, 64),    dim3(256), 0, stream, x, Wt, a_ws, asump);
    hipLaunchKernelGGL(k25_asum,   dim3(16),       dim3(256), 0, stream, asump, asum);
    hipMemsetAsync(d_out, 0, (size_t)out_size * sizeof(float), stream);
    hipLaunchKernelGGL(k3_vlad,    dim3(4, 64, 2), dim3(256), 0, stream, x, a_ws, out);
    hipLaunchKernelGGL(k4a_rownorm, dim3(1024),    dim3(256), 0, stream, out, asum, cent, rn2);
    hipLaunchKernelGGL(k4b_gn,     dim3(64),       dim3(64),  0, stream, rn2, gn);
    hipLaunchKernelGGL(k4c_final,  dim3(2048),     dim3(256), 0, stream, out, asum, cent, rn2, gn);
}

// Round 2
// 461.044 us; speedup vs baseline: 1.6070x; 1.6070x over previous
//
#include <hip/hip_runtime.h>
#include <math.h>

#define EPSF 1e-12f

// N=64, C=512, P=1600, K=64
// ws layout (bytes):
//   a_t  bf16 [n][k][p] : 13,107,200   @ 0
//   xbt  bf16 [n][p][c] : 104,857,600  @ 13,107,200
//   Wb   bf16 [k][c]    : 65,536       @ 117,964,800
//   rn   f32  [n][p]    : 409,600      @ 118,030,336
//   asum f32  [n][k]    : 16,384       @ 118,439,936
//   rn2  f32  [n][k]    : 16,384       @ 118,456,320
//   gn   f32  [n]       : 256          @ 118,472,704

typedef short bf16x8 __attribute__((ext_vector_type(8)));
typedef float f32x4  __attribute__((ext_vector_type(4)));

__device__ __forceinline__ ushort f2b(float x) {
    unsigned u = __float_as_uint(x);
    return (ushort)((u + 0x7fffu + ((u >> 16) & 1u)) >> 16);
}

// ------------------------------------------------- K0: Wb[k][c] = bf16(W)
__global__ __launch_bounds__(256) void k0_wb(const float* __restrict__ W,
                                             ushort* __restrict__ Wb) {
    int i = blockIdx.x * 256 + threadIdx.x;
    if (i < 64 * 512) Wb[i] = f2b(W[i]);
}

// ------------------------------------------------- K1: xbt[n][p][c] = bf16(x), rn[n][p]
// grid (100 ptiles of 16, 64 n), 256 thr. LDS tile transpose, fused sum-of-squares.
__global__ __launch_bounds__(256) void k1_transpose(const float* __restrict__ x,
                                                    ushort* __restrict__ xbt,
                                                    float* __restrict__ rn) {
    const int n = blockIdx.y, p0 = blockIdx.x * 16;
    const int tid = threadIdx.x;
    __shared__ float tile[512 * 17];
    __shared__ float ssred[16 * 17];
    {
        const int cr = tid >> 2, pc4 = tid & 3;
        const float* src = x + ((size_t)n * 512 + cr) * 1600 + p0 + pc4 * 4;
        #pragma unroll
        for (int it = 0; it < 8; it++) {
            float4 v = *(const float4*)(src + (size_t)it * 64 * 1600);
            float* d = &tile[(cr + it * 64) * 17 + pc4 * 4];
            d[0] = v.x; d[1] = v.y; d[2] = v.z; d[3] = v.w;
        }
    }
    __syncthreads();
    {
        const int pl = tid >> 4, cc = tid & 15;
        float ss = 0.f;
        ushort buf[32] __attribute__((aligned(16)));
        #pragma unroll
        for (int i = 0; i < 32; i++) {
            float v = tile[(cc * 32 + i) * 17 + pl];
            ss = fmaf(v, v, ss);
            buf[i] = f2b(v);
        }
        ushort* dst = xbt + ((size_t)n * 1600 + p0 + pl) * 512 + cc * 32;
        #pragma unroll
        for (int ch = 0; ch < 4; ch++)
            ((uint4*)dst)[ch] = ((const uint4*)buf)[ch];
        ssred[pl * 17 + cc] = ss;
    }
    __syncthreads();
    if (tid < 16) {
        float s = 0.f;
        #pragma unroll
        for (int i = 0; i < 16; i++) s += ssred[tid * 17 + i];
        rn[n * 1600 + p0 + tid] = 1.f / fmaxf(sqrtf(s), EPSF);
    }
}

// ------------------------------------------------- K2a: MFMA GEMM1 + fused softmax
// D[p][k] per wave: 16p x 64k (4 n-tiles), K=512. grid (25, 64), 256 thr.
// A = xbt[p][c] (b128), B = Wb[k][c] (b128). Epilogue: softmax over k, a' = a*rn
// -> bf16 a_t[n][k][p] via LDS bounce; asum[n][k] via atomics.
__global__ __launch_bounds__(256) void k2a_gemm1(const ushort* __restrict__ xbt,
                                                 const ushort* __restrict__ Wb,
                                                 const float* __restrict__ rn,
                                                 ushort* __restrict__ a_t,
                                                 float* __restrict__ asum) {
    const int n = blockIdx.y;
    const int p0 = blockIdx.x * 64;
    const int wv = threadIdx.x >> 6, lane = threadIdx.x & 63;
    const int q = lane >> 4, l15 = lane & 15;
    const int pw = p0 + wv * 16;

    const ushort* arow = xbt + ((size_t)n * 1600 + pw + l15) * 512 + q * 8;
    const ushort* brow = Wb + l15 * 512 + q * 8;

    f32x4 acc[4] = {};
    for (int kc = 0; kc < 512; kc += 32) {
        bf16x8 af = *(const bf16x8*)(arow + kc);
        #pragma unroll
        for (int nt = 0; nt < 4; nt++) {
            bf16x8 bf = *(const bf16x8*)(brow + nt * 16 * 512 + kc);
            acc[nt] = __builtin_amdgcn_mfma_f32_16x16x32_bf16(af, bf, acc[nt], 0, 0, 0);
        }
    }

    // rows handled by this lane: p = pw + q*4 + r
    float rnv[4];
    #pragma unroll
    for (int r = 0; r < 4; r++) rnv[r] = rn[n * 1600 + pw + q * 4 + r];

    float v[4][4];  // [nt][r]
    float mx[4] = {-3.4e38f, -3.4e38f, -3.4e38f, -3.4e38f};
    #pragma unroll
    for (int nt = 0; nt < 4; nt++)
        #pragma unroll
        for (int r = 0; r < 4; r++) {
            v[nt][r] = acc[nt][r] * rnv[r];
            mx[r] = fmaxf(mx[r], v[nt][r]);
        }
    #pragma unroll
    for (int s = 1; s <= 8; s <<= 1)
        #pragma unroll
        for (int r = 0; r < 4; r++) mx[r] = fmaxf(mx[r], __shfl_xor(mx[r], s, 64));
    float sm[4] = {0.f, 0.f, 0.f, 0.f};
    #pragma unroll
    for (int nt = 0; nt < 4; nt++)
        #pragma unroll
        for (int r = 0; r < 4; r++) { v[nt][r] = __expf(v[nt][r] - mx[r]); sm[r] += v[nt][r]; }
    #pragma unroll
    for (int s = 1; s <= 8; s <<= 1)
        #pragma unroll
        for (int r = 0; r < 4; r++) sm[r] += __shfl_xor(sm[r], s, 64);
    float inv[4];
    #pragma unroll
    for (int r = 0; r < 4; r++) inv[r] = 1.f / sm[r];
    #pragma unroll
    for (int nt = 0; nt < 4; nt++)
        #pragma unroll
        for (int r = 0; r < 4; r++) v[nt][r] *= inv[r];  // a (softmax prob)

    // asum partials: per nt column k = nt*16 + l15, sum over this wave's 16 rows
    #pragma unroll
    for (int nt = 0; nt < 4; nt++) {
        float t = v[nt][0] + v[nt][1] + v[nt][2] + v[nt][3];
        t += __shfl_xor(t, 16, 64);
        t += __shfl_xor(t, 32, 64);
        if (lane < 16) atomicAdd(&asum[n * 64 + nt * 16 + lane], t);
    }

    // a' = a*rn -> bf16, LDS bounce [k][p_local] then coalesced-ish global write
    __shared__ ushort abuf[4][64 * 24];
    #pragma unroll
    for (int nt = 0; nt < 4; nt++)
        #pragma unroll
        for (int r = 0; r < 4; r++)
            abuf[wv][(nt * 16 + l15) * 24 + q * 4 + r] = f2b(v[nt][r] * rnv[r]);
    __syncthreads();
    ushort* dst = a_t + ((size_t)n * 64 + lane) * 1600 + pw;
    const ushort* srcl = &abuf[wv][lane * 24];
    *(uint4*)(dst)     = *(const uint4*)(srcl);
    *(uint4*)(dst + 8) = *(const uint4*)(srcl + 8);
}

// ------------------------------------------------- K3: MFMA GEMM2
// D[k][c]: block 64k x 256c, K=320 p per chunk. grid (2 ctiles, 64 n, 5 pchunks).
// A = a_t[k][p] bf16 (b128); B = x[c][p] fp32 -> bf16 on the fly. atomicAdd to out.
__global__ __launch_bounds__(256) void k3_gemm2(const ushort* __restrict__ a_t,
                                                const float* __restrict__ x,
                                                float* __restrict__ out) {
    const int n = blockIdx.y;
    const int c0 = blockIdx.x * 256;
    const int p0 = blockIdx.z * 320;
    const int wv = threadIdx.x >> 6, lane = threadIdx.x & 63;
    const int q = lane >> 4, l15 = lane & 15;
    const int cw = c0 + wv * 64;

    const ushort* abase = a_t + ((size_t)n * 64 + l15) * 1600 + p0 + q * 8;
    const float*  xbase = x + ((size_t)n * 512 + cw + l15) * 1600 + p0 + q * 8;

    f32x4 acc[4][4] = {};
    for (int pc = 0; pc < 320; pc += 32) {
        bf16x8 af[4];
        #pragma unroll
        for (int mt = 0; mt < 4; mt++)
            af[mt] = *(const bf16x8*)(abase + (size_t)mt * 16 * 1600 + pc);
        bf16x8 bf[4];
        #pragma unroll
        for (int nt = 0; nt < 4; nt++) {
            const float* xr = xbase + (size_t)nt * 16 * 1600 + pc;
            float4 f0 = *(const float4*)(xr);
            float4 f1 = *(const float4*)(xr + 4);
            bf16x8 b;
            b[0] = (short)f2b(f0.x); b[1] = (short)f2b(f0.y);
            b[2] = (short)f2b(f0.z); b[3] = (short)f2b(f0.w);
            b[4] = (short)f2b(f1.x); b[5] = (short)f2b(f1.y);
            b[6] = (short)f2b(f1.z); b[7] = (short)f2b(f1.w);
            bf[nt] = b;
        }
        #pragma unroll
        for (int mt = 0; mt < 4; mt++)
            #pragma unroll
            for (int nt = 0; nt < 4; nt++)
                acc[mt][nt] = __builtin_amdgcn_mfma_f32_16x16x32_bf16(af[mt], bf[nt], acc[mt][nt], 0, 0, 0);
    }
    float* ob = out + (size_t)n * 32768 + cw + l15;
    #pragma unroll
    for (int mt = 0; mt < 4; mt++)
        #pragma unroll
        for (int nt = 0; nt < 4; nt++)
            #pragma unroll
            for (int r = 0; r < 4; r++)
                atomicAdd(ob + (mt * 16 + q * 4 + r) * 512 + nt * 16, acc[mt][nt][r]);
}

// ------------------------------------------------- K4a: rownorm2[n,k] = sum_c (raw - asum*cent)^2
__global__ __launch_bounds__(256) void k4a_rownorm(const float* __restrict__ vraw,
                                                   const float* __restrict__ asum,
                                                   const float* __restrict__ cent,
                                                   float* __restrict__ rn2) {
    int row  = blockIdx.x * 4 + (threadIdx.x >> 6);
    int lane = threadIdx.x & 63;
    int k = row & 63;
    const float4* vp = (const float4*)(vraw + (size_t)row * 512 + lane * 8);
    const float4* cp = (const float4*)(cent + k * 512 + lane * 8);
    float as = asum[row];
    float4 v0 = vp[0], v1 = vp[1], c0 = cp[0], c1 = cp[1];
    float s = 0.f, t;
    t = v0.x - as * c0.x; s = fmaf(t, t, s);
    t = v0.y - as * c0.y; s = fmaf(t, t, s);
    t = v0.z - as * c0.z; s = fmaf(t, t, s);
    t = v0.w - as * c0.w; s = fmaf(t, t, s);
    t = v1.x - as * c1.x; s = fmaf(t, t, s);
    t = v1.y - as * c1.y; s = fmaf(t, t, s);
    t = v1.z - as * c1.z; s = fmaf(t, t, s);
    t = v1.w - as * c1.w; s = fmaf(t, t, s);
    #pragma unroll
    for (int off = 32; off > 0; off >>= 1) s += __shfl_down(s, off, 64);
    if (lane == 0) rn2[row] = s;
}

// ------------------------------------------------- K4b: gn[n]
__global__ __launch_bounds__(64) void k4b_gn(const float* __restrict__ rn2,
                                             float* __restrict__ gn) {
    int n = blockIdx.x, k = threadIdx.x;
    float t = rn2[n * 64 + k];
    float d = fmaxf(sqrtf(t), EPSF);
    float r = t / (d * d);
    #pragma unroll
    for (int off = 32; off > 0; off >>= 1) r += __shfl_down(r, off, 64);
    if (k == 0) gn[n] = fmaxf(sqrtf(r), EPSF);
}

// ------------------------------------------------- K4c: final normalize
__global__ __launch_bounds__(256) void k4c_final(float* __restrict__ vout,
                                                 const float* __restrict__ asum,
                                                 const float* __restrict__ cent,
                                                 const float* __restrict__ rn2,
                                                 const float* __restrict__ gn) {
    int gid = blockIdx.x * 256 + threadIdx.x;
    int idx4 = gid * 4;
    int row = idx4 >> 9;
    int n = row >> 6, k = row & 63, c = idx4 & 511;
    float4 v  = *(const float4*)(vout + idx4);
    float4 cv = *(const float4*)(cent + k * 512 + c);
    float as = asum[row];
    float inv = 1.f / (fmaxf(sqrtf(rn2[row]), EPSF) * gn[n]);
    v.x = (v.x - as * cv.x) * inv;
    v.y = (v.y - as * cv.y) * inv;
    v.z = (v.z - as * cv.z) * inv;
    v.w = (v.w - as * cv.w) * inv;
    *(float4*)(vout + idx4) = v;
}

// -------------------------------------------------
extern "C" void kernel_launch(void* const* d_in, const int* in_sizes, int n_in,
                              void* d_out, int out_size, void* d_ws, size_t ws_size,
                              hipStream_t stream) {
    const float* x    = (const float*)d_in[0];
    const float* W    = (const float*)d_in[1];
    const float* cent = (const float*)d_in[2];
    float* out = (float*)d_out;
    char* ws = (char*)d_ws;

    ushort* a_t  = (ushort*)(ws + 0);
    ushort* xbt  = (ushort*)(ws + 13107200);
    ushort* Wb   = (ushort*)(ws + 117964800);
    float*  rn   = (float*)(ws + 118030336);
    float*  asum = (float*)(ws + 118439936);
    float*  rn2  = (float*)(ws + 118456320);
    float*  gn   = (float*)(ws + 118472704);

    hipMemsetAsync(asum, 0, 64 * 64 * sizeof(float), stream);
    hipMemsetAsync(d_out, 0, (size_t)out_size * sizeof(float), stream);

    hipLaunchKernelGGL(k0_wb,       dim3(128),        dim3(256), 0, stream, W, Wb);
    hipLaunchKernelGGL(k1_transpose, dim3(100, 64),   dim3(256), 0, stream, x, xbt, rn);
    hipLaunchKernelGGL(k2a_gemm1,   dim3(25, 64),     dim3(256), 0, stream, xbt, Wb, rn, a_t, asum);
    hipLaunchKernelGGL(k3_gemm2,    dim3(2, 64, 5),   dim3(256), 0, stream, a_t, x, out);
    hipLaunchKernelGGL(k4a_rownorm, dim3(1024),       dim3(256), 0, stream, out, asum, cent, rn2);
    hipLaunchKernelGGL(k4b_gn,      dim3(64),         dim3(64),  0, stream, rn2, gn);
    hipLaunchKernelGGL(k4c_final,   dim3(2048),       dim3(256), 0, stream, out, asum, cent, rn2, gn);
}